// Round 9
// baseline (111.188 us; speedup 1.0000x reference)
//
#include <hip/hip_runtime.h>
#include <hip/hip_bf16.h>
#include <stdint.h>

typedef __attribute__((ext_vector_type(8))) __bf16 bf16x8;
typedef __attribute__((ext_vector_type(4))) float f32x4;

static constexpr int Bb = 32, Ss = 512, Dd = 1024, Rr = 256;

__device__ __forceinline__ void gload_lds16(const void* g, void* l) {
  __builtin_amdgcn_global_load_lds(
      (const __attribute__((address_space(1))) void*)g,
      (__attribute__((address_space(3))) void*)l, 16, 0, 0);
}

// ---- prep: Bt[512][1024] bf16. rows 0-255 = L^T, rows 256-511 = R ----------
__global__ __launch_bounds__(256) void prep_kernel(
    const float* __restrict__ L, const float* __restrict__ R,
    __bf16* __restrict__ Bt) {
  int i = blockIdx.x * 256 + threadIdx.x;  // 0 .. 512*1024-1 exactly
  int n = i >> 10;
  int d = i & (Dd - 1);
  float v = (n < Rr) ? L[d * Rr + n] : R[(size_t)(n - Rr) * Dd + d];
  Bt[i] = (__bf16)v;
}

// ---- stage 1: C[16384,512] = batch_f32[16384,1024] x Bt[512,1024]^T --------
// NO LDS, NO BARRIERS: direct-fragment GEMM. Each wave owns a 64x64 output
// tile and runs fully independently (2048 waves, 8/CU). Fragments loaded
// straight from global: B panel (1MB bf16) is L2-resident; A (64MB fp32) is
// L3-resident on replays. 1-deep software pipeline with NAMED even/odd reg
// stages (no runtime-indexed arrays -> no scratch). Loads of step k+1 are
// issued before the MFMAs of step k; compiler inserts counted vmcnt.
__global__ __launch_bounds__(256, 2) void proj_gemm(
    const float* __restrict__ batch,
    const __bf16* __restrict__ Bt,   // [512][1024]
    __bf16* __restrict__ outL,       // [16384][256]
    __bf16* __restrict__ outR) {     // [16384][256]
  // XCD-chunked bijective remap (512 = 8*64)
  const int s = ((blockIdx.x & 7) << 6) + (blockIdx.x >> 3);
  const int mt = s >> 1;   // 0..255
  const int nt2 = s & 1;   // 0..1
  const int wave = threadIdx.x >> 6;  // 0..3
  const int lane = threadIdx.x & 63;

  const int m0 = mt * 64;                   // wave-shared rows (L1 reuse)
  const int n0 = nt2 * 256 + wave * 64;     // per-wave 64 cols

  // per-lane base pointers (fragment layout: row=lane&15, k=(lane>>4)*8+j)
  const float* ap = batch + (size_t)(m0 + (lane & 15)) * Dd + (lane >> 4) * 8;
  const __bf16* bp = Bt + (size_t)(n0 + (lane & 15)) * Dd + (lane >> 4) * 8;

  f32x4 acc[4][4] = {};

  // named pipeline stages (8 f32x4 A regs + 4 bf16x8 B regs each)
  f32x4 a0_0, a0_1, a0_2, a0_3, a0_4, a0_5, a0_6, a0_7;
  f32x4 a1_0, a1_1, a1_2, a1_3, a1_4, a1_5, a1_6, a1_7;
  bf16x8 b0_0, b0_1, b0_2, b0_3;
  bf16x8 b1_0, b1_1, b1_2, b1_3;

#define LOADA(S, k)                                                    \
  do {                                                                 \
    const float* p_ = ap + (k) * 32;                                   \
    S##_0 = *(const f32x4*)(p_);                                       \
    S##_1 = *(const f32x4*)(p_ + 4);                                   \
    S##_2 = *(const f32x4*)(p_ + 16 * Dd);                             \
    S##_3 = *(const f32x4*)(p_ + 16 * Dd + 4);                         \
    S##_4 = *(const f32x4*)(p_ + 32 * Dd);                             \
    S##_5 = *(const f32x4*)(p_ + 32 * Dd + 4);                         \
    S##_6 = *(const f32x4*)(p_ + 48 * Dd);                             \
    S##_7 = *(const f32x4*)(p_ + 48 * Dd + 4);                         \
  } while (0)
#define LOADB(S, k)                                                    \
  do {                                                                 \
    const __bf16* p_ = bp + (k) * 32;                                  \
    S##_0 = *(const bf16x8*)(p_);                                      \
    S##_1 = *(const bf16x8*)(p_ + 16 * Dd);                            \
    S##_2 = *(const bf16x8*)(p_ + 32 * Dd);                            \
    S##_3 = *(const bf16x8*)(p_ + 48 * Dd);                            \
  } while (0)
#define CVT(dst, lo, hi)                                               \
  do {                                                                 \
    dst[0] = (__bf16)lo[0]; dst[1] = (__bf16)lo[1];                    \
    dst[2] = (__bf16)lo[2]; dst[3] = (__bf16)lo[3];                    \
    dst[4] = (__bf16)hi[0]; dst[5] = (__bf16)hi[1];                    \
    dst[6] = (__bf16)hi[2]; dst[7] = (__bf16)hi[3];                    \
  } while (0)
#define STEP(AS, BS)                                                   \
  do {                                                                 \
    bf16x8 af[4];                                                      \
    CVT(af[0], AS##_0, AS##_1); CVT(af[1], AS##_2, AS##_3);            \
    CVT(af[2], AS##_4, AS##_5); CVT(af[3], AS##_6, AS##_7);            \
    bf16x8 bf_[4] = {BS##_0, BS##_1, BS##_2, BS##_3};                  \
    _Pragma("unroll") for (int m = 0; m < 4; ++m)                      \
        _Pragma("unroll") for (int n = 0; n < 4; ++n)                  \
            acc[m][n] = __builtin_amdgcn_mfma_f32_16x16x32_bf16(       \
                af[m], bf_[n], acc[m][n], 0, 0, 0);                    \
  } while (0)

  LOADA(a0, 0);
  LOADB(b0, 0);
#pragma unroll 1
  for (int kk = 0; kk < 32; kk += 2) {
    if (kk + 1 < 32) {
      LOADA(a1, kk + 1);
      LOADB(b1, kk + 1);
    }
    STEP(a0, b0);
    if (kk + 2 < 32) {
      LOADA(a0, kk + 2);
      LOADB(b0, kk + 2);
    }
    STEP(a1, b1);
  }
#undef LOADA
#undef LOADB
#undef CVT
#undef STEP

  // epilogue: nt2 selects output half; C/D layout col=lane&15, row grp
  __bf16* out = nt2 ? outR : outL;
  const int col = lane & 15, rgrp = lane >> 4;
#pragma unroll
  for (int m = 0; m < 4; ++m) {
    int r0 = m0 + m * 16 + rgrp * 4;
#pragma unroll
    for (int n = 0; n < 4; ++n) {
      int c = wave * 64 + n * 16 + col;
#pragma unroll
      for (int i = 0; i < 4; ++i)
        out[(size_t)(r0 + i) * Rr + c] = (__bf16)acc[m][n][i];
    }
  }
}

// ---- stage 2: logits[b] = left[b] @ right[b]^T + bias ----------------------
// Per batch: C[512,512] f32 = A[512,256] x Bt[512,256], both bf16 K-contig.
// 64x128 tile, BK=64, single-buffer 24KB, swizzled. 1024 blocks (4/CU).
__global__ __launch_bounds__(256, 4) void score_gemm(
    const __bf16* __restrict__ left,
    const __bf16* __restrict__ right,
    const float* __restrict__ biasp,
    float* __restrict__ out) {
  const int nt = blockIdx.x;  // 0..3
  const int mt = blockIdx.y;  // 0..7
  const int bz = blockIdx.z;  // 0..31
  const __bf16* A = left + (size_t)bz * Ss * Rr;
  const __bf16* B = right + (size_t)bz * Ss * Rr;
  float* O = out + (size_t)bz * Ss * Ss;
  const int m0 = mt * 64, n0 = nt * 128;

  __shared__ __align__(16) char smem[24576];
  // A bf16 [64][64] @ 0 (8KB), B bf16 [128][64] @ 8192 (16KB)

  const int t = threadIdx.x;
  const int lane = t & 63;
  const int wave = t >> 6;
  const int wr = wave >> 1, wc = wave & 1;

  f32x4 acc[2][4] = {};

  for (int it = 0; it < 4; ++it) {
    const int k0 = it * 64;
    __syncthreads();
#pragma unroll
    for (int q = 0; q < 2; ++q) {  // A: 512 granules
      int e = q * 256 + t;
      int row = e >> 3, g = e & 7;
      int gsrc = g ^ (row & 7);
      gload_lds16(A + (size_t)(m0 + row) * Rr + k0 + gsrc * 8, smem + e * 16);
    }
#pragma unroll
    for (int q = 0; q < 4; ++q) {  // B: 1024 granules
      int e = q * 256 + t;
      int row = e >> 3, g = e & 7;
      int gsrc = g ^ (row & 7);
      gload_lds16(B + (size_t)(n0 + row) * Rr + k0 + gsrc * 8,
                  smem + 8192 + e * 16);
    }
    __syncthreads();

#pragma unroll
    for (int kk = 0; kk < 2; ++kk) {
      bf16x8 a[2], b[4];
#pragma unroll
      for (int m = 0; m < 2; ++m) {
        int row = wr * 32 + m * 16 + (lane & 15);
        int g = kk * 4 + (lane >> 4);
        a[m] = *(const bf16x8*)(smem + (row * 8 + (g ^ (row & 7))) * 16);
      }
#pragma unroll
      for (int n = 0; n < 4; ++n) {
        int row = wc * 64 + n * 16 + (lane & 15);
        int g = kk * 4 + (lane >> 4);
        b[n] = *(const bf16x8*)(smem + 8192 +
                                (row * 8 + (g ^ (row & 7))) * 16);
      }
#pragma unroll
      for (int m = 0; m < 2; ++m)
#pragma unroll
        for (int n = 0; n < 4; ++n)
          acc[m][n] = __builtin_amdgcn_mfma_f32_16x16x32_bf16(a[m], b[n],
                                                              acc[m][n], 0, 0, 0);
    }
  }

  const float bias = *biasp;
  const int col = lane & 15, rgrp = lane >> 4;
#pragma unroll
  for (int m = 0; m < 2; ++m) {
    int r0 = m0 + wr * 32 + m * 16 + rgrp * 4;
#pragma unroll
    for (int n = 0; n < 4; ++n) {
      int c = n0 + wc * 64 + n * 16 + col;
#pragma unroll
      for (int i = 0; i < 4; ++i)
        O[(size_t)(r0 + i) * Ss + c] = acc[m][n][i] + bias;
    }
  }
}

extern "C" void kernel_launch(void* const* d_in, const int* in_sizes, int n_in,
                              void* d_out, int out_size, void* d_ws,
                              size_t ws_size, hipStream_t stream) {
  const float* batch = (const float*)d_in[0];  // [32][512][1024]
  const float* projL = (const float*)d_in[1];  // [1024][256]
  const float* projR = (const float*)d_in[2];  // [256][1024]
  const float* bias = (const float*)d_in[3];   // [1]
  float* out = (float*)d_out;                  // [32][512][512]

  char* ws = (char*)d_ws;
  __bf16* left = (__bf16*)(ws);                 // 8,388,608 B [16384][256]
  __bf16* right = (__bf16*)(ws + 8388608);      // 8,388,608 B [16384][256]
  __bf16* Btc = (__bf16*)(ws + 16777216);       // 1,048,576 B [512][1024]

  prep_kernel<<<dim3(2048), dim3(256), 0, stream>>>(projL, projR, Btc);
  proj_gemm<<<dim3(512), dim3(256), 0, stream>>>(batch, Btc, left, right);
  score_gemm<<<dim3(4, 8, 32), dim3(256), 0, stream>>>(left, right, bias, out);
}

// Round 11
// 54.048 us; speedup vs baseline: 2.0572x; 2.0572x over previous
//
#include <hip/hip_runtime.h>
#include <hip/hip_bf16.h>
#include <stdint.h>

typedef __attribute__((ext_vector_type(8))) __bf16 bf16x8;
typedef __attribute__((ext_vector_type(4))) float f32x4;

static constexpr int Bb = 32, Ss = 512, Dd = 1024, Rr = 256;

__device__ __forceinline__ void gload_lds16(const void* g, void* l) {
  __builtin_amdgcn_global_load_lds(
      (const __attribute__((address_space(1))) void*)g,
      (__attribute__((address_space(3))) void*)l, 16, 0, 0);
}

// ---- prep: Bt[512][1024] bf16. rows 0-255 = L^T, rows 256-511 = R ----------
__global__ __launch_bounds__(256) void prep_kernel(
    const float* __restrict__ L, const float* __restrict__ R,
    __bf16* __restrict__ Bt) {
  int i = blockIdx.x * 256 + threadIdx.x;  // 0 .. 512*1024-1 exactly
  int n = i >> 10;
  int d = i & (Dd - 1);
  float v = (n < Rr) ? L[d * Rr + n] : R[(size_t)(n - Rr) * Dd + d];
  Bt[i] = (__bf16)v;
}

// ---- stage 1: C[16384,512] = batch_f32[16384,1024] x Bt[512,1024]^T --------
// Score-identical tiling (64x128, BK=64, 4 waves, 1024 blocks) with BOTH
// operands double-buffered (48KB -> 3 blk/CU) and __syncthreads()-ONLY
// synchronization (compiler drains vmcnt+lgkmcnt at every sync -> every
// LDS buffer hand-off is fully fenced; no raw-barrier races, cf. R9).
// Per K-tile: {issue A-regs + B gload_lds for t+1} -> compute(t) ->
// cvt+writeA(t+1) -> __syncthreads. A-loads retire via compiler-counted
// vmcnt at writeA; B DMAs land during compute, drained ~free at the sync.
// Swizzle g^(row&7), 16B granules, both sides (rule 21).
__global__ __launch_bounds__(256, 3) void proj_gemm(
    const float* __restrict__ batch,
    const __bf16* __restrict__ Bt,   // [512][1024]
    __bf16* __restrict__ outL,       // [16384][256]
    __bf16* __restrict__ outR) {     // [16384][256]
  // XCD-chunked (bijective, 1024 = 8*128): 4 nt-siblings consecutive -> one
  // XCD shares each A-panel in its L2.
  const int s = ((blockIdx.x & 7) << 7) + (blockIdx.x >> 3);
  const int mt = s >> 2;  // 0..255
  const int nt = s & 3;   // 0..3
  const int m0 = mt * 64, n0 = nt * 128;

  __shared__ __align__(16) char smem[49152];
  // A bf16 [64][64]:  buf b at b*8192          (8KB each)
  // B bf16 [128][64]: buf b at 16384 + b*16384 (16KB each)

  const int t = threadIdx.x;
  const int lane = t & 63;
  const int wave = t >> 6;
  const int wr = wave >> 1, wc = wave & 1;  // 2M x 2N waves, 32x64 each

  f32x4 acc[2][4] = {};
  f32x4 areg[4];  // one K-tile of A per thread, in flight across compute

  // A staging: [64 rows][8 granules]; thread t: row=t>>2, granules {ag, ag+4}
  const int arow = t >> 2, ag = t & 3;
  const int ags = ag ^ (arow & 7);  // slot of granule ag; ag+4 -> ags^4

  auto issueA = [&](int k0) {
    const float* src = batch + (size_t)(m0 + arow) * Dd + k0 + ag * 8;
    areg[0] = *(const f32x4*)src;
    areg[1] = *(const f32x4*)(src + 4);
    areg[2] = *(const f32x4*)(src + 32);
    areg[3] = *(const f32x4*)(src + 36);
  };
  auto writeA = [&](int buf) {
    char* Ab = smem + buf * 8192;
    bf16x8 v0, v1;
    v0[0] = (__bf16)areg[0][0]; v0[1] = (__bf16)areg[0][1];
    v0[2] = (__bf16)areg[0][2]; v0[3] = (__bf16)areg[0][3];
    v0[4] = (__bf16)areg[1][0]; v0[5] = (__bf16)areg[1][1];
    v0[6] = (__bf16)areg[1][2]; v0[7] = (__bf16)areg[1][3];
    v1[0] = (__bf16)areg[2][0]; v1[1] = (__bf16)areg[2][1];
    v1[2] = (__bf16)areg[2][2]; v1[3] = (__bf16)areg[2][3];
    v1[4] = (__bf16)areg[3][0]; v1[5] = (__bf16)areg[3][1];
    v1[6] = (__bf16)areg[3][2]; v1[7] = (__bf16)areg[3][3];
    *(bf16x8*)(Ab + (arow * 8 + ags) * 16) = v0;
    *(bf16x8*)(Ab + (arow * 8 + (ags ^ 4)) * 16) = v1;
  };
  auto stageB = [&](int buf, int k0) {
    char* Bbuf = smem + 16384 + buf * 16384;
#pragma unroll
    for (int p = 0; p < 4; ++p) {
      int e = p * 256 + t;
      int row = e >> 3, g = e & 7;
      int gs = g ^ (row & 7);  // inverse-swizzled SOURCE, linear LDS dest
      gload_lds16(Bt + (size_t)(n0 + row) * Dd + k0 + gs * 8,
                  Bbuf + e * 16);
    }
  };
  auto compute = [&](int buf) {
    const char* Ab = smem + buf * 8192;
    const char* Bbuf = smem + 16384 + buf * 16384;
#pragma unroll
    for (int kk = 0; kk < 2; ++kk) {
      const int g = kk * 4 + (lane >> 4);
      bf16x8 a[2], b[4];
#pragma unroll
      for (int m = 0; m < 2; ++m) {
        int row = wr * 32 + m * 16 + (lane & 15);
        a[m] = *(const bf16x8*)(Ab + (row * 8 + (g ^ (row & 7))) * 16);
      }
#pragma unroll
      for (int n = 0; n < 4; ++n) {
        int row = wc * 64 + n * 16 + (lane & 15);
        b[n] = *(const bf16x8*)(Bbuf + (row * 8 + (g ^ (row & 7))) * 16);
      }
#pragma unroll
      for (int m = 0; m < 2; ++m)
#pragma unroll
        for (int n = 0; n < 4; ++n)
          acc[m][n] = __builtin_amdgcn_mfma_f32_16x16x32_bf16(a[m], b[n],
                                                              acc[m][n], 0, 0, 0);
    }
  };

  // prologue: tile 0 into buf 0 (A loads first; writeA's compiler-counted
  // vmcnt retires them; the sync drains the B DMAs + ds_writes)
  issueA(0);
  stageB(0, 0);
  writeA(0);
  __syncthreads();

#pragma unroll 1
  for (int tt = 0; tt < 16; ++tt) {
    const int buf = tt & 1;
    if (tt < 15) {
      issueA(tt * 64 + 64);            // 4 gloads -> regs, under compute
      stageB(buf ^ 1, tt * 64 + 64);   // 4 DMAs -> other B buf, under compute
    }
    compute(buf);                      // 12 ds_read_b128 + 16 MFMA / wave
    if (tt < 15) writeA(buf ^ 1);      // counted vmcnt (A only) + cvt + 2 ds_write
    __syncthreads();                   // full drain: publishes buf^1 safely
  }

  // epilogue: nt 0-1 -> outL, 2-3 -> outR (C/D: col=lane&15, row=grp*4+i)
  __bf16* out = (n0 < Rr) ? outL : outR;
  const int cb = n0 & (Rr - 1);
  const int col = lane & 15, rgrp = lane >> 4;
#pragma unroll
  for (int m = 0; m < 2; ++m) {
    int r0 = m0 + wr * 32 + m * 16 + rgrp * 4;
#pragma unroll
    for (int n = 0; n < 4; ++n) {
      int c = cb + wc * 64 + n * 16 + col;
#pragma unroll
      for (int i = 0; i < 4; ++i)
        out[(size_t)(r0 + i) * Rr + c] = (__bf16)acc[m][n][i];
    }
  }
}

// ---- stage 2: logits[b] = left[b] @ right[b]^T + bias ----------------------
// Per batch: C[512,512] f32 = A[512,256] x Bt[512,256], both bf16 K-contig.
// 64x128 tile, BK=64, single-buffer 24KB, swizzled. 1024 blocks (4/CU).
// UNCHANGED control: measured ~614 TF.
__global__ __launch_bounds__(256, 4) void score_gemm(
    const __bf16* __restrict__ left,
    const __bf16* __restrict__ right,
    const float* __restrict__ biasp,
    float* __restrict__ out) {
  const int nt = blockIdx.x;  // 0..3
  const int mt = blockIdx.y;  // 0..7
  const int bz = blockIdx.z;  // 0..31
  const __bf16* A = left + (size_t)bz * Ss * Rr;
  const __bf16* B = right + (size_t)bz * Ss * Rr;
  float* O = out + (size_t)bz * Ss * Ss;
  const int m0 = mt * 64, n0 = nt * 128;

  __shared__ __align__(16) char smem[24576];
  // A bf16 [64][64] @ 0 (8KB), B bf16 [128][64] @ 8192 (16KB)

  const int t = threadIdx.x;
  const int lane = t & 63;
  const int wave = t >> 6;
  const int wr = wave >> 1, wc = wave & 1;

  f32x4 acc[2][4] = {};

  for (int it = 0; it < 4; ++it) {
    const int k0 = it * 64;
    __syncthreads();
#pragma unroll
    for (int q = 0; q < 2; ++q) {  // A: 512 granules
      int e = q * 256 + t;
      int row = e >> 3, g = e & 7;
      int gsrc = g ^ (row & 7);
      gload_lds16(A + (size_t)(m0 + row) * Rr + k0 + gsrc * 8, smem + e * 16);
    }
#pragma unroll
    for (int q = 0; q < 4; ++q) {  // B: 1024 granules
      int e = q * 256 + t;
      int row = e >> 3, g = e & 7;
      int gsrc = g ^ (row & 7);
      gload_lds16(B + (size_t)(n0 + row) * Rr + k0 + gsrc * 8,
                  smem + 8192 + e * 16);
    }
    __syncthreads();

#pragma unroll
    for (int kk = 0; kk < 2; ++kk) {
      bf16x8 a[2], b[4];
#pragma unroll
      for (int m = 0; m < 2; ++m) {
        int row = wr * 32 + m * 16 + (lane & 15);
        int g = kk * 4 + (lane >> 4);
        a[m] = *(const bf16x8*)(smem + (row * 8 + (g ^ (row & 7))) * 16);
      }
#pragma unroll
      for (int n = 0; n < 4; ++n) {
        int row = wc * 64 + n * 16 + (lane & 15);
        int g = kk * 4 + (lane >> 4);
        b[n] = *(const bf16x8*)(smem + 8192 +
                                (row * 8 + (g ^ (row & 7))) * 16);
      }
#pragma unroll
      for (int m = 0; m < 2; ++m)
#pragma unroll
        for (int n = 0; n < 4; ++n)
          acc[m][n] = __builtin_amdgcn_mfma_f32_16x16x32_bf16(a[m], b[n],
                                                              acc[m][n], 0, 0, 0);
    }
  }

  const float bias = *biasp;
  const int col = lane & 15, rgrp = lane >> 4;
#pragma unroll
  for (int m = 0; m < 2; ++m) {
    int r0 = m0 + wr * 32 + m * 16 + rgrp * 4;
#pragma unroll
    for (int n = 0; n < 4; ++n) {
      int c = n0 + wc * 64 + n * 16 + col;
#pragma unroll
      for (int i = 0; i < 4; ++i)
        O[(size_t)(r0 + i) * Ss + c] = acc[m][n][i] + bias;
    }
  }
}

extern "C" void kernel_launch(void* const* d_in, const int* in_sizes, int n_in,
                              void* d_out, int out_size, void* d_ws,
                              size_t ws_size, hipStream_t stream) {
  const float* batch = (const float*)d_in[0];  // [32][512][1024]
  const float* projL = (const float*)d_in[1];  // [1024][256]
  const float* projR = (const float*)d_in[2];  // [256][1024]
  const float* bias = (const float*)d_in[3];   // [1]
  float* out = (float*)d_out;                  // [32][512][512]

  char* ws = (char*)d_ws;
  __bf16* left = (__bf16*)(ws);                 // 8,388,608 B [16384][256]
  __bf16* right = (__bf16*)(ws + 8388608);      // 8,388,608 B [16384][256]
  __bf16* Btc = (__bf16*)(ws + 16777216);       // 1,048,576 B [512][1024]

  prep_kernel<<<dim3(2048), dim3(256), 0, stream>>>(projL, projR, Btc);
  proj_gemm<<<dim3(1024), dim3(256), 0, stream>>>(batch, Btc, left, right);
  score_gemm<<<dim3(4, 8, 32), dim3(256), 0, stream>>>(left, right, bias, out);
}